// Round 6
// baseline (551.064 us; speedup 1.0000x reference)
//
#include <hip/hip_runtime.h>

#define N_NODES 4096
#define D_MODEL 128
#define QK_DIM  32
#define NHEAD   8
#define QKH     (QK_DIM * NHEAD)   // 256
#define VH      (D_MODEL * NHEAD)  // 1024

typedef _Float16 f16;
typedef _Float16 f16x8 __attribute__((ext_vector_type(8)));
typedef float    f32x4 __attribute__((ext_vector_type(4)));
typedef unsigned long long u64;

static __device__ __forceinline__ unsigned int pack_f16x2(float a, float b) {
    union { f16 h; unsigned short s; } ua, ub;
    ua.h = (f16)a; ub.h = (f16)b;
    return ((unsigned int)ub.s << 16) | (unsigned int)ua.s;
}

// ---- fused prep: mask->bits | x->f16 | Wq,Wk->Wqkt | Wv->Wvt | Wo->Wot ----
__global__ __launch_bounds__(256) void prep_kernel(
    const int* __restrict__ mask, u64* __restrict__ mbits,
    const float* __restrict__ x, f16* __restrict__ xf,
    const float* __restrict__ Wq, const float* __restrict__ Wk,
    f16* __restrict__ Wqkt,
    const float* __restrict__ Wv, f16* __restrict__ Wvt,
    const float* __restrict__ Wo, f16* __restrict__ Wot) {
    const int b = blockIdx.x, t = threadIdx.x;
    if (b < 1024) {
        const int gw = b * 4 + (t >> 6), lane = t & 63;
        for (int word = gw; word < 262144; word += 4096) {
            const int v = mask[(size_t)word * 64 + lane];
            const u64 bits = __ballot(v != 0);
            if (lane == 0) mbits[word] = bits;
        }
    } else if (b < 1280) {
        const int tid = (b - 1024) * 256 + t;
        const float2* x2 = (const float2*)x;
        unsigned int* u = (unsigned int*)xf;
        for (int i = tid; i < 262144; i += 65536) {
            const float2 v = x2[i];
            u[i] = pack_f16x2(v.x, v.y);
        }
    } else if (b < 1408) {
        const int tid = (b - 1280) * 256 + t;           // 32768 elems
        const int n = tid >> 7, k = tid & 127;
        Wqkt[tid] = (f16)Wq[(size_t)k * QKH + n];
    } else if (b < 1536) {
        const int tid = (b - 1408) * 256 + t;           // 32768 elems
        const int n = tid >> 7, k = tid & 127;
        Wqkt[32768 + tid] = (f16)Wk[(size_t)k * QKH + n];
    } else if (b < 2048) {
        const int tid = (b - 1536) * 256 + t;           // 131072 elems
        const int n = tid >> 7, k = tid & 127;
        Wvt[tid] = (f16)Wv[(size_t)k * VH + n];
    } else {
        const int tid = (b - 2048) * 256 + t;           // 131072 elems
        const int n = tid >> 10, k = tid & 1023;
        Wot[tid] = (f16)Wo[(size_t)k * D_MODEL + n];
    }
}

// ---- GEMM body: C[M,N] = A[M,K](f16) @ Wt[N,K]^T (+bias) -----------------
// MODE 0: f16 row-major (DUAL_BIAS: n<256?b1:b2)
// MODE 1: f16 transposed out[n][m] + bias (LDS bounce, coalesced stores)
// MODE 3: f32 partials (no bias), k-split by bz, out offset bz*M*N
template <int OUT_MODE, bool DUAL_BIAS>
static __device__ __forceinline__ void gemm_body(
    const f16* __restrict__ A, const f16* __restrict__ Wt,
    const float* __restrict__ b1, const float* __restrict__ b2,
    void* __restrict__ outp, int M, int N, int K,
    int bx, int by, int bz, int nz) {
    const int t = threadIdx.x;
    const int w = t >> 6, lane = t & 63, quad = lane >> 4, col = lane & 15;
    const int mb = by * 64 + (w & 1) * 32;
    const int nb = bx * 64 + (w >> 1) * 32;

    const f32x4 zero = {0.f, 0.f, 0.f, 0.f};
    f32x4 acc[2][2];
    acc[0][0] = zero; acc[0][1] = zero; acc[1][0] = zero; acc[1][1] = zero;

    const int ksteps = K >> 5;
    const int kper = ksteps / nz;
    const int ks0 = bz * kper, ks1 = ks0 + kper;
    for (int ks = ks0; ks < ks1; ++ks) {
        const int ko = ks * 32 + quad * 8;
        const f16x8 a0 = *reinterpret_cast<const f16x8*>(&A[(size_t)(mb + col) * K + ko]);
        const f16x8 a1 = *reinterpret_cast<const f16x8*>(&A[(size_t)(mb + 16 + col) * K + ko]);
        const f16x8 b0 = *reinterpret_cast<const f16x8*>(&Wt[(size_t)(nb + col) * K + ko]);
        const f16x8 bb = *reinterpret_cast<const f16x8*>(&Wt[(size_t)(nb + 16 + col) * K + ko]);
        acc[0][0] = __builtin_amdgcn_mfma_f32_16x16x32_f16(a0, b0, acc[0][0], 0, 0, 0);
        acc[1][0] = __builtin_amdgcn_mfma_f32_16x16x32_f16(a1, b0, acc[1][0], 0, 0, 0);
        acc[0][1] = __builtin_amdgcn_mfma_f32_16x16x32_f16(a0, bb, acc[0][1], 0, 0, 0);
        acc[1][1] = __builtin_amdgcn_mfma_f32_16x16x32_f16(a1, bb, acc[1][1], 0, 0, 0);
    }

    if constexpr (OUT_MODE == 1) {
        __shared__ f16 ct[64][68];
#pragma unroll
        for (int sub = 0; sub < 2; ++sub)
#pragma unroll
            for (int snb = 0; snb < 2; ++snb) {
                const int nl = (w >> 1) * 32 + snb * 16 + col;
                const float bv = b1[nb + snb * 16 + col];
                const int ml0 = (w & 1) * 32 + sub * 16 + quad * 4;
                uint2 u;
                u.x = pack_f16x2(acc[sub][snb][0] + bv, acc[sub][snb][1] + bv);
                u.y = pack_f16x2(acc[sub][snb][2] + bv, acc[sub][snb][3] + bv);
                *reinterpret_cast<uint2*>(&ct[nl][ml0]) = u;
            }
        __syncthreads();
        const int nl = t >> 2, qtr = t & 3;
        const int n = bx * 64 + nl;
        const int m0 = by * 64 + qtr * 16;
        const f16x8 v0 = *reinterpret_cast<const f16x8*>(&ct[nl][qtr * 16]);
        const f16x8 v1 = *reinterpret_cast<const f16x8*>(&ct[nl][qtr * 16 + 8]);
        *reinterpret_cast<f16x8*>(&((f16*)outp)[(size_t)n * M + m0]) = v0;
        *reinterpret_cast<f16x8*>(&((f16*)outp)[(size_t)n * M + m0 + 8]) = v1;
    } else {
#pragma unroll
        for (int sub = 0; sub < 2; ++sub)
#pragma unroll
            for (int snb = 0; snb < 2; ++snb) {
                const int n = nb + snb * 16 + col;
                float bv = 0.f;
                if (OUT_MODE != 3)
                    bv = (DUAL_BIAS && n >= 256) ? b2[n - 256] : b1[n];
                if (OUT_MODE == 0) {
#pragma unroll
                    for (int reg = 0; reg < 4; ++reg) {
                        const int m = mb + sub * 16 + quad * 4 + reg;
                        const float v  = acc[sub][snb][reg] + bv;
                        const float v2 = __shfl_xor(v, 1);
                        if ((lane & 1) == 0)
                            *reinterpret_cast<unsigned int*>(
                                &((f16*)outp)[(size_t)m * N + (n & ~1)]) = pack_f16x2(v, v2);
                    }
                } else {
                    float* ob = (float*)outp + (size_t)bz * M * N;
#pragma unroll
                    for (int reg = 0; reg < 4; ++reg) {
                        const int m = mb + sub * 16 + quad * 4 + reg;
                        ob[(size_t)m * N + n] = acc[sub][snb][reg] + bv;
                    }
                }
            }
    }
}

// ---- fused QK + V projections (one launch, 24x64 grid) -------------------
__global__ __launch_bounds__(256) void proj_kernel(
    const f16* __restrict__ xf, const f16* __restrict__ Wqkt,
    const f16* __restrict__ Wvt,
    const float* __restrict__ bq, const float* __restrict__ bk,
    const float* __restrict__ bv,
    f16* __restrict__ QKf, f16* __restrict__ Vtp) {
    if (blockIdx.x < 8)
        gemm_body<0, true>(xf, Wqkt, bq, bk, QKf, N_NODES, 512, D_MODEL,
                           blockIdx.x, blockIdx.y, 0, 1);
    else
        gemm_body<1, false>(xf, Wvt, bv, bv, Vtp, N_NODES, VH, D_MODEL,
                            blockIdx.x - 8, blockIdx.y, 0, 1);
}

// ---- out-projection with k-split -----------------------------------------
__global__ __launch_bounds__(256) void outproj_kernel(
    const f16* __restrict__ Rf, const f16* __restrict__ Wot,
    float* __restrict__ outp) {
    gemm_body<3, false>(Rf, Wot, nullptr, nullptr, outp, N_NODES, D_MODEL, VH,
                        blockIdx.x, blockIdx.y, blockIdx.z, gridDim.z);
}

// ---- MFMA flash attention, software-pipelined, fenced raw barriers -------
// Grid (64 q-tiles, 8 heads, split). Block 256 = 4 waves.
// REGISTER/OCCUPANCY HISTORY (do not revisit):
//   (256,3) + 2-deep K AND V prefetch -> ~200 VGPR, 285 MB spill, 252us (R1).
//   (256,2) same source -> no spill but WRONG (absmax 0.107), deterministic,
//     fence-independent -> the (256,2) regime is bad; avoid.
//   (256,3) + 2-deep K, 1-deep V -> CORRECT, 172us (R5), but total regs
//     (~136-150 incl AGPR) land in the (128,170] bin -> HW occupancy steps
//     at {64,128,256} regs (m69) -> only 2 waves/SIMD, Occupancy 28.5%,
//     57% stall.
//   THIS VERSION: 1-deep K prefetch (frees 16 VGPR; K for tile T+1 issued
//     right after tile T's QK MFMAs, lands during epilogue+barrier+PV
//     ~700cy >= L2 latency) + __launch_bounds__(256,4) -> total ~120 <= 128
//     -> 4 waves/SIMD. Watch WRITE_SIZE: if it jumps, the 128 cap spilled.
// Barrier: one fused asm {s_waitcnt lgkmcnt(0); s_barrier} with "memory"
// clobber (s_barrier builtin alone is not a memory fence in LLVM's model),
// + sched_barrier(0). No vmcnt drain: register-destined global prefetches
// stay in flight across barriers. ps double-buffered so ONE barrier per tile
// suffices (write->barrier->read; WAR two tiles later is fenced by the
// intervening barrier's lgkmcnt(0) drain of the prior reads).
#define FENCED_BARRIER() do { \
    asm volatile("s_waitcnt lgkmcnt(0)\n\ts_barrier" ::: "memory"); \
    __builtin_amdgcn_sched_barrier(0); \
} while (0)

#define LOADK(KB, J) do { _Pragma("unroll") \
    for (int km = 0; km < 4; ++km) \
        KB[km] = *reinterpret_cast<const f16x8*>( \
            &QKf[(size_t)((J) + 4 * col + km) * 512 + 256 + h * 32 + quad * 8]); } while (0)

#define LOADV(VB, J) do { _Pragma("unroll") \
    for (int t2 = 0; t2 < 2; ++t2) { _Pragma("unroll") \
        for (int ks = 0; ks < 2; ++ks) \
            VB[t2][ks] = *reinterpret_cast<const f16x8*>( \
                &Vt[(size_t)(h * 128 + 32 * w + 16 * t2 + col) * N_NODES + \
                    (J) + ks * 32 + quad * 8]); } } while (0)

#define LOADM(J) do { _Pragma("unroll") \
    for (int reg = 0; reg < 4; ++reg) \
        mr[reg] = mbits[(size_t)(q0 + 16 * w + quad * 4 + reg) * 64 + ((J) >> 6)]; } while (0)

#define LOADB(J) do { _Pragma("unroll") \
    for (int reg = 0; reg < 4; ++reg) { \
        const float4 b4 = *reinterpret_cast<const float4*>( \
            &bias[(size_t)(q0 + 16 * w + quad * 4 + reg) * N_NODES + (J) + 4 * col]); \
        bfr[reg][0] = b4.x; bfr[reg][1] = b4.y; \
        bfr[reg][2] = b4.z; bfr[reg][3] = b4.w; } } while (0)

// One 64-key tile. Single kb register set (1-deep prefetch: QK consumes it,
// then immediately reloads it for tile PJ). PSEL: LDS ps buffer (0/1).
// PJ/POK: K prefetch j + guard. VJ: current tile j for the V set.
// MJ/MOK: mask/bias prefetch (consumed in epilogue BEFORE the reload).
#define TILE(PSEL, PJ, POK, VJ, MJ, MOK) do { \
    f32x4 S[4]; \
    _Pragma("unroll") \
    for (int km = 0; km < 4; ++km) \
        S[km] = __builtin_amdgcn_mfma_f32_16x16x32_f16(qa, kb[km], zero, 0, 0, 0); \
    if (POK) LOADK(kb, PJ); \
    LOADV(vbT, VJ); \
    _Pragma("unroll") \
    for (int reg = 0; reg < 4; ++reg) { \
        float pk[4]; \
        _Pragma("unroll") \
        for (int km = 0; km < 4; ++km) { \
            float base = C8; \
            if (h == 0) base = __builtin_fmaf(bfr[reg][km], L2E, C8); \
            const float tt = __builtin_fmaf(S[km][reg], SCL, base); \
            const bool msk = (mr[reg] >> (4 * col + km)) & 1ull; \
            pk[km] = msk ? 0.f : __builtin_amdgcn_exp2f(tt); \
        } \
        uint2 u; \
        u.x = pack_f16x2(pk[0], pk[1]); \
        u.y = pack_f16x2(pk[2], pk[3]); \
        *reinterpret_cast<uint2*>(&ps[PSEL][16 * w + quad * 4 + reg][4 * col]) = u; \
    } \
    if (MOK) { LOADM(MJ); if (h == 0) LOADB(MJ); } \
    FENCED_BARRIER(); \
    __builtin_amdgcn_s_setprio(1); \
    _Pragma("unroll") \
    for (int ks = 0; ks < 2; ++ks) { _Pragma("unroll") \
        for (int qs = 0; qs < 4; ++qs) { \
            const f16x8 pa = *reinterpret_cast<const f16x8*>( \
                &ps[PSEL][16 * qs + col][ks * 32 + quad * 8]); \
            if (qs == w) \
                Lacc = __builtin_amdgcn_mfma_f32_16x16x32_f16(pa, onesv, Lacc, 0, 0, 0); \
            O[qs][0] = __builtin_amdgcn_mfma_f32_16x16x32_f16(pa, vbT[0][ks], O[qs][0], 0, 0, 0); \
            O[qs][1] = __builtin_amdgcn_mfma_f32_16x16x32_f16(pa, vbT[1][ks], O[qs][1], 0, 0, 0); \
        } } \
    __builtin_amdgcn_s_setprio(0); \
} while (0)

__global__ __launch_bounds__(256, 4) void attn_kernel(
    const f16* __restrict__ QKf, const f16* __restrict__ Vt,
    const u64* __restrict__ mbits, const float* __restrict__ bias,
    f16* __restrict__ R, f16* __restrict__ part, float* __restrict__ lsum) {
    const int h  = blockIdx.y;
    const int q0 = blockIdx.x * 64;
    const int t  = threadIdx.x;
    const int w = t >> 6, lane = t & 63, quad = lane >> 4, col = lane & 15;

    __shared__ f16 ps[2][64][72];   // double-buffered P tile
    __shared__ float ls[64];        // row sums for final normalization

    const f16x8 qa = *reinterpret_cast<const f16x8*>(
        &QKf[(size_t)(q0 + 16 * w + col) * 512 + h * 32 + quad * 8]);

    const f32x4 zero = {0.f, 0.f, 0.f, 0.f};
    f32x4 O[4][2];               // [qs][t2]: q 16qs+quad*4+reg, d 32w+16t2+col
#pragma unroll
    for (int qs = 0; qs < 4; ++qs) { O[qs][0] = zero; O[qs][1] = zero; }
    f32x4 Lacc = zero;
    const f16 one1 = (f16)1.f;
    const f16x8 onesv = {one1, one1, one1, one1, one1, one1, one1, one1};

    const float L2E = 1.4426950408889634f;
    const float SCL = 0.17677669529663687f * 1.4426950408889634f;  // scale*log2e
    const float C8  = -8.f * 1.4426950408889634f;                  // -MFIX*log2e
    const int jspan = N_NODES / gridDim.z;
    const int jbegin = blockIdx.z * jspan, jend = jbegin + jspan;

    f16x8 kb[4];
    f16x8 vbT[2][2];
    u64   mr[4];
    float bfr[4][4];

    // prologue: one tile of K, one tile of mask/bias (V loads in-tile)
    LOADK(kb, jbegin);
    LOADM(jbegin);
    if (h == 0) LOADB(jbegin);

    for (int j0 = jbegin; j0 < jend; j0 += 128) {
        TILE(0, j0 + 64,  j0 + 64  < jend, j0,      j0 + 64,  true);
        TILE(1, j0 + 128, j0 + 128 < jend, j0 + 64, j0 + 128, j0 + 128 < jend);
    }

    // --- exchange row sums, normalize, store ---
    if (col == 0) {
#pragma unroll
        for (int reg = 0; reg < 4; ++reg)
            ls[16 * w + quad * 4 + reg] = Lacc[reg];
    }
    __syncthreads();

    if (gridDim.z == 1) {
#pragma unroll
        for (int qs = 0; qs < 4; ++qs)
#pragma unroll
            for (int reg = 0; reg < 4; ++reg) {
                const float inv = 1.f / ls[16 * qs + quad * 4 + reg];
                const int q = q0 + 16 * qs + quad * 4 + reg;
#pragma unroll
                for (int t2 = 0; t2 < 2; ++t2)
                    R[(size_t)q * VH + h * 128 + 32 * w + 16 * t2 + col] =
                        (f16)(O[qs][t2][reg] * inv);
            }
    } else {
        const size_t seg = (size_t)(blockIdx.z * NHEAD + h) * N_NODES;
#pragma unroll
        for (int qs = 0; qs < 4; ++qs)
#pragma unroll
            for (int reg = 0; reg < 4; ++reg) {
                const float inv = 1.f / ls[16 * qs + quad * 4 + reg];
                const int q = q0 + 16 * qs + quad * 4 + reg;
#pragma unroll
                for (int t2 = 0; t2 < 2; ++t2)
                    part[(seg + q) * 128 + 32 * w + 16 * t2 + col] =
                        (f16)(O[qs][t2][reg] * inv);
            }
        if (col == 0) {
#pragma unroll
            for (int reg = 0; reg < 4; ++reg)
                lsum[seg + q0 + 16 * w + quad * 4 + reg] = Lacc[reg];
        }
    }
}

// ---- merge split partials: R = sum_z l_z*Obar_z / sum_z l_z --------------
// vectorized: 8 d-elements per thread (f16x8 loads/stores)
__global__ __launch_bounds__(256) void merge_kernel(
    const f16* __restrict__ part, const float* __restrict__ lsum,
    f16* __restrict__ R, int split) {
    const int tid = blockIdx.x * 256 + threadIdx.x;   // 8*4096*16
    const int d8 = tid & 15, q = (tid >> 4) & 4095, h = tid >> 16;
    float acc[8];
#pragma unroll
    for (int i = 0; i < 8; ++i) acc[i] = 0.f;
    float den = 0.f;
    for (int z = 0; z < split; ++z) {
        const size_t seg = (size_t)(z * NHEAD + h) * N_NODES + q;
        const float l = lsum[seg];
        const f16x8 v = *reinterpret_cast<const f16x8*>(&part[seg * 128 + 8 * d8]);
#pragma unroll
        for (int i = 0; i < 8; ++i) acc[i] += l * (float)v[i];
        den += l;
    }
    const float inv = 1.f / den;
    f16x8 o;
#pragma unroll
    for (int i = 0; i < 8; ++i) o[i] = (f16)(acc[i] * inv);
    *reinterpret_cast<f16x8*>(&R[(size_t)q * VH + h * 128 + 8 * d8]) = o;
}

// ---- reduce out-proj k-split partials + bias (float4) --------------------
__global__ __launch_bounds__(256) void reduce_out_kernel(
    const float* __restrict__ part, const float* __restrict__ bo,
    float* __restrict__ out) {
    const int i = (blockIdx.x * 256 + threadIdx.x) * 4;   // 4096*128 floats
    float4 s = *reinterpret_cast<const float4*>(&bo[i & 127]);
#pragma unroll
    for (int z = 0; z < 4; ++z) {
        const float4 p = *reinterpret_cast<const float4*>(
            &part[(size_t)z * N_NODES * D_MODEL + i]);
        s.x += p.x; s.y += p.y; s.z += p.z; s.w += p.w;
    }
    *reinterpret_cast<float4*>(&out[i]) = s;
}

extern "C" void kernel_launch(void* const* d_in, const int* in_sizes, int n_in,
                              void* d_out, int out_size, void* d_ws, size_t ws_size,
                              hipStream_t stream) {
    const float* x  = (const float*)d_in[0];
    const int*   mk = (const int*)d_in[1];
    const float* eb = (const float*)d_in[2];
    const float* Wq = (const float*)d_in[3];
    const float* bq = (const float*)d_in[4];
    const float* Wk = (const float*)d_in[5];
    const float* bk = (const float*)d_in[6];
    const float* Wv = (const float*)d_in[7];
    const float* bv = (const float*)d_in[8];
    const float* Wo = (const float*)d_in[9];
    const float* bo = (const float*)d_in[10];
    float* out = (float*)d_out;

    char* ws = (char*)d_ws;
    u64* mbits = (u64*)(ws);                                    // 2 MB
    f16* xf16 = (f16*)(ws + 2097152);                           // 1 MB
    f16* Wqkt = (f16*)(ws + 3145728);                           // 128 KB
    f16* Wvt  = (f16*)(ws + 3276800);                           // 256 KB
    f16* Wot  = (f16*)(ws + 3538944);                           // 256 KB
    f16* QKf  = (f16*)(ws + 3801088);                           // 4 MB
    f16* Vt   = (f16*)(ws + 7995392);                           // 8 MB
    f16* Rf   = (f16*)(ws + 16384000);                          // 8 MB -> 24772608
    float* out_part = (float*)(ws + 24772608);                  // 8 MB -> 33161216
    float* lsum = (float*)(ws + 33161216);                      // 512 KB -> 33685504
    f16* part = (f16*)(ws + 33685504);                          // split*8MB -> 67239936

    // config from ws_size only (constant across calls -> graph-safe)
    int split = 1;
    if (ws_size >= 67239936ull) split = 4;
    else if (ws_size >= 50462720ull) split = 2;
    const bool ksplit_out = ws_size >= 33161216ull;

    prep_kernel<<<2560, 256, 0, stream>>>(mk, mbits, x, xf16, Wq, Wk, Wqkt, Wv, Wvt, Wo, Wot);

    proj_kernel<<<dim3(24, 64), 256, 0, stream>>>(xf16, Wqkt, Wvt, bq, bk, bv, QKf, Vt);

    attn_kernel<<<dim3(64, 8, split), 256, 0, stream>>>(QKf, Vt, mbits, eb, Rf, part, lsum);
    if (split > 1)
        merge_kernel<<<2048, 256, 0, stream>>>(part, lsum, Rf, split);

    if (ksplit_out) {
        outproj_kernel<<<dim3(2, 64, 4), 256, 0, stream>>>(Rf, Wot, out_part);
        reduce_out_kernel<<<512, 256, 0, stream>>>(out_part, bo, out);
    } else {
        // fallback: single-pass out-projection via k-split of 1
        outproj_kernel<<<dim3(2, 64, 1), 256, 0, stream>>>(Rf, Wot, out_part);
        reduce_out_kernel<<<512, 256, 0, stream>>>(out_part, bo, out);
    }
}

// Round 8
// 367.475 us; speedup vs baseline: 1.4996x; 1.4996x over previous
//
#include <hip/hip_runtime.h>

#define N_NODES 4096
#define D_MODEL 128
#define QK_DIM  32
#define NHEAD   8
#define QKH     (QK_DIM * NHEAD)   // 256
#define VH      (D_MODEL * NHEAD)  // 1024

typedef _Float16 f16;
typedef _Float16 f16x8 __attribute__((ext_vector_type(8)));
typedef float    f32x4 __attribute__((ext_vector_type(4)));
typedef unsigned long long u64;

static __device__ __forceinline__ unsigned int pack_f16x2(float a, float b) {
    union { f16 h; unsigned short s; } ua, ub;
    ua.h = (f16)a; ub.h = (f16)b;
    return ((unsigned int)ub.s << 16) | (unsigned int)ua.s;
}

// ---- fused prep: mask->bits | x->f16 | Wq,Wk->Wqkt | Wv->Wvt | Wo->Wot ----
__global__ __launch_bounds__(256) void prep_kernel(
    const int* __restrict__ mask, u64* __restrict__ mbits,
    const float* __restrict__ x, f16* __restrict__ xf,
    const float* __restrict__ Wq, const float* __restrict__ Wk,
    f16* __restrict__ Wqkt,
    const float* __restrict__ Wv, f16* __restrict__ Wvt,
    const float* __restrict__ Wo, f16* __restrict__ Wot) {
    const int b = blockIdx.x, t = threadIdx.x;
    if (b < 1024) {
        const int gw = b * 4 + (t >> 6), lane = t & 63;
        for (int word = gw; word < 262144; word += 4096) {
            const int v = mask[(size_t)word * 64 + lane];
            const u64 bits = __ballot(v != 0);
            if (lane == 0) mbits[word] = bits;
        }
    } else if (b < 1280) {
        const int tid = (b - 1024) * 256 + t;
        const float2* x2 = (const float2*)x;
        unsigned int* u = (unsigned int*)xf;
        for (int i = tid; i < 262144; i += 65536) {
            const float2 v = x2[i];
            u[i] = pack_f16x2(v.x, v.y);
        }
    } else if (b < 1408) {
        const int tid = (b - 1280) * 256 + t;           // 32768 elems
        const int n = tid >> 7, k = tid & 127;
        Wqkt[tid] = (f16)Wq[(size_t)k * QKH + n];
    } else if (b < 1536) {
        const int tid = (b - 1408) * 256 + t;           // 32768 elems
        const int n = tid >> 7, k = tid & 127;
        Wqkt[32768 + tid] = (f16)Wk[(size_t)k * QKH + n];
    } else if (b < 2048) {
        const int tid = (b - 1536) * 256 + t;           // 131072 elems
        const int n = tid >> 7, k = tid & 127;
        Wvt[tid] = (f16)Wv[(size_t)k * VH + n];
    } else {
        const int tid = (b - 2048) * 256 + t;           // 131072 elems
        const int n = tid >> 10, k = tid & 1023;
        Wot[tid] = (f16)Wo[(size_t)k * D_MODEL + n];
    }
}

// ---- GEMM body: C[M,N] = A[M,K](f16) @ Wt[N,K]^T (+bias) -----------------
// MODE 0: f16 row-major (DUAL_BIAS: n<256?b1:b2)
// MODE 1: f16 transposed out[n][m] + bias (LDS bounce, coalesced stores)
// MODE 3: f32 partials (no bias), k-split by bz, out offset bz*M*N
template <int OUT_MODE, bool DUAL_BIAS>
static __device__ __forceinline__ void gemm_body(
    const f16* __restrict__ A, const f16* __restrict__ Wt,
    const float* __restrict__ b1, const float* __restrict__ b2,
    void* __restrict__ outp, int M, int N, int K,
    int bx, int by, int bz, int nz) {
    const int t = threadIdx.x;
    const int w = t >> 6, lane = t & 63, quad = lane >> 4, col = lane & 15;
    const int mb = by * 64 + (w & 1) * 32;
    const int nb = bx * 64 + (w >> 1) * 32;

    const f32x4 zero = {0.f, 0.f, 0.f, 0.f};
    f32x4 acc[2][2];
    acc[0][0] = zero; acc[0][1] = zero; acc[1][0] = zero; acc[1][1] = zero;

    const int ksteps = K >> 5;
    const int kper = ksteps / nz;
    const int ks0 = bz * kper, ks1 = ks0 + kper;
    for (int ks = ks0; ks < ks1; ++ks) {
        const int ko = ks * 32 + quad * 8;
        const f16x8 a0 = *reinterpret_cast<const f16x8*>(&A[(size_t)(mb + col) * K + ko]);
        const f16x8 a1 = *reinterpret_cast<const f16x8*>(&A[(size_t)(mb + 16 + col) * K + ko]);
        const f16x8 b0 = *reinterpret_cast<const f16x8*>(&Wt[(size_t)(nb + col) * K + ko]);
        const f16x8 bb = *reinterpret_cast<const f16x8*>(&Wt[(size_t)(nb + 16 + col) * K + ko]);
        acc[0][0] = __builtin_amdgcn_mfma_f32_16x16x32_f16(a0, b0, acc[0][0], 0, 0, 0);
        acc[1][0] = __builtin_amdgcn_mfma_f32_16x16x32_f16(a1, b0, acc[1][0], 0, 0, 0);
        acc[0][1] = __builtin_amdgcn_mfma_f32_16x16x32_f16(a0, bb, acc[0][1], 0, 0, 0);
        acc[1][1] = __builtin_amdgcn_mfma_f32_16x16x32_f16(a1, bb, acc[1][1], 0, 0, 0);
    }

    if constexpr (OUT_MODE == 1) {
        __shared__ f16 ct[64][68];
#pragma unroll
        for (int sub = 0; sub < 2; ++sub)
#pragma unroll
            for (int snb = 0; snb < 2; ++snb) {
                const int nl = (w >> 1) * 32 + snb * 16 + col;
                const float bv = b1[nb + snb * 16 + col];
                const int ml0 = (w & 1) * 32 + sub * 16 + quad * 4;
                uint2 u;
                u.x = pack_f16x2(acc[sub][snb][0] + bv, acc[sub][snb][1] + bv);
                u.y = pack_f16x2(acc[sub][snb][2] + bv, acc[sub][snb][3] + bv);
                *reinterpret_cast<uint2*>(&ct[nl][ml0]) = u;
            }
        __syncthreads();
        const int nl = t >> 2, qtr = t & 3;
        const int n = bx * 64 + nl;
        const int m0 = by * 64 + qtr * 16;
        const f16x8 v0 = *reinterpret_cast<const f16x8*>(&ct[nl][qtr * 16]);
        const f16x8 v1 = *reinterpret_cast<const f16x8*>(&ct[nl][qtr * 16 + 8]);
        *reinterpret_cast<f16x8*>(&((f16*)outp)[(size_t)n * M + m0]) = v0;
        *reinterpret_cast<f16x8*>(&((f16*)outp)[(size_t)n * M + m0 + 8]) = v1;
    } else {
#pragma unroll
        for (int sub = 0; sub < 2; ++sub)
#pragma unroll
            for (int snb = 0; snb < 2; ++snb) {
                const int n = nb + snb * 16 + col;
                float bv = 0.f;
                if (OUT_MODE != 3)
                    bv = (DUAL_BIAS && n >= 256) ? b2[n - 256] : b1[n];
                if (OUT_MODE == 0) {
#pragma unroll
                    for (int reg = 0; reg < 4; ++reg) {
                        const int m = mb + sub * 16 + quad * 4 + reg;
                        const float v  = acc[sub][snb][reg] + bv;
                        const float v2 = __shfl_xor(v, 1);
                        if ((lane & 1) == 0)
                            *reinterpret_cast<unsigned int*>(
                                &((f16*)outp)[(size_t)m * N + (n & ~1)]) = pack_f16x2(v, v2);
                    }
                } else {
                    float* ob = (float*)outp + (size_t)bz * M * N;
#pragma unroll
                    for (int reg = 0; reg < 4; ++reg) {
                        const int m = mb + sub * 16 + quad * 4 + reg;
                        ob[(size_t)m * N + n] = acc[sub][snb][reg] + bv;
                    }
                }
            }
    }
}

// ---- fused QK + V projections (one launch, 24x64 grid) -------------------
__global__ __launch_bounds__(256) void proj_kernel(
    const f16* __restrict__ xf, const f16* __restrict__ Wqkt,
    const f16* __restrict__ Wvt,
    const float* __restrict__ bq, const float* __restrict__ bk,
    const float* __restrict__ bv,
    f16* __restrict__ QKf, f16* __restrict__ Vtp) {
    if (blockIdx.x < 8)
        gemm_body<0, true>(xf, Wqkt, bq, bk, QKf, N_NODES, 512, D_MODEL,
                           blockIdx.x, blockIdx.y, 0, 1);
    else
        gemm_body<1, false>(xf, Wvt, bv, bv, Vtp, N_NODES, VH, D_MODEL,
                            blockIdx.x - 8, blockIdx.y, 0, 1);
}

// ---- out-projection with k-split -----------------------------------------
__global__ __launch_bounds__(256) void outproj_kernel(
    const f16* __restrict__ Rf, const f16* __restrict__ Wot,
    float* __restrict__ outp) {
    gemm_body<3, false>(Rf, Wot, nullptr, nullptr, outp, N_NODES, D_MODEL, VH,
                        blockIdx.x, blockIdx.y, blockIdx.z, gridDim.z);
}

// ---- MFMA flash attention, 128-q-row tiles, 8 waves ----------------------
// Grid (32 q-tiles, 8 heads, split). Block 512 = 8 waves.
// HISTORY (do not revisit):
//   R1 (256,3) 2-deep K+V: spill 285MB, 252us. R2/R3 (256,2): WRONG (0.107,
//   fence-independent). R5 (256,3) 2-deep K + in-tile V: CORRECT 172.8us.
//   R6 (256,4): 573MB spill, 366us -- 128-reg bin unreachable. R7 V-ahead
//   dbuf: NaN. => register-pipeline variants around the fenced barrier are a
//   fragile compiler regime; R5's sync/prefetch structure is FROZEN.
// THIS VERSION: geometry-only change vs R5. q-tile 64->128, 8 waves.
//   V traffic = q_tiles x 8MB invariant: 64 tiles -> 512MB L2/L3 per launch
//   (R5); 32 tiles -> 256MB. Wave w: QK rows [16w,16w+16) (same as R5);
//   PV: wq=w>>2 selects q-half, wd=w&3 selects d-slice; waves w and w+4 load
//   the SAME V fragments -> L1 absorbs the duplicate. Per-wave register
//   demand identical to R5 (~150); (512,2) caps 256 -> no spill. 1 block/CU
//   (8 waves/CU ~= R5's 9.2). Grid 32x8x4 = 1024 blocks = exactly 4 rounds.
// Sync structure IDENTICAL to R5: 2-deep K register sets, in-tile V load,
// ps double-buffered, ONE fused {s_waitcnt lgkmcnt(0); s_barrier} "memory"
// asm + sched_barrier(0) per tile, no vmcnt drain.
#define FENCED_BARRIER() do { \
    asm volatile("s_waitcnt lgkmcnt(0)\n\ts_barrier" ::: "memory"); \
    __builtin_amdgcn_sched_barrier(0); \
} while (0)

#define LOADK(KB, J) do { _Pragma("unroll") \
    for (int km = 0; km < 4; ++km) \
        KB[km] = *reinterpret_cast<const f16x8*>( \
            &QKf[(size_t)((J) + 4 * col + km) * 512 + 256 + h * 32 + quad * 8]); } while (0)

#define LOADV(VB, J) do { _Pragma("unroll") \
    for (int t2 = 0; t2 < 2; ++t2) { _Pragma("unroll") \
        for (int ks = 0; ks < 2; ++ks) \
            VB[t2][ks] = *reinterpret_cast<const f16x8*>( \
                &Vt[(size_t)(h * 128 + 32 * wd + 16 * t2 + col) * N_NODES + \
                    (J) + ks * 32 + quad * 8]); } } while (0)

#define LOADM(J) do { _Pragma("unroll") \
    for (int reg = 0; reg < 4; ++reg) \
        mr[reg] = mbits[(size_t)(q0 + 16 * w + quad * 4 + reg) * 64 + ((J) >> 6)]; } while (0)

#define LOADB(J) do { _Pragma("unroll") \
    for (int reg = 0; reg < 4; ++reg) { \
        const float4 b4 = *reinterpret_cast<const float4*>( \
            &bias[(size_t)(q0 + 16 * w + quad * 4 + reg) * N_NODES + (J) + 4 * col]); \
        bfr[reg][0] = b4.x; bfr[reg][1] = b4.y; \
        bfr[reg][2] = b4.z; bfr[reg][3] = b4.w; } } while (0)

// One 64-key tile. KB: this tile's K register set (also prefetch target two
// tiles ahead). PSEL: LDS ps buffer (0/1). PJ/POK: K prefetch j + guard.
// VJ: current tile j for the shared V set. MJ/MOK: mask/bias prefetch.
#define TILE(KB, PSEL, PJ, POK, VJ, MJ, MOK) do { \
    f32x4 S[4]; \
    _Pragma("unroll") \
    for (int km = 0; km < 4; ++km) \
        S[km] = __builtin_amdgcn_mfma_f32_16x16x32_f16(qa, KB[km], zero, 0, 0, 0); \
    if (POK) LOADK(KB, PJ); \
    LOADV(vbT, VJ); \
    _Pragma("unroll") \
    for (int reg = 0; reg < 4; ++reg) { \
        float pk[4]; \
        _Pragma("unroll") \
        for (int km = 0; km < 4; ++km) { \
            float base = C8; \
            if (h == 0) base = __builtin_fmaf(bfr[reg][km], L2E, C8); \
            const float tt = __builtin_fmaf(S[km][reg], SCL, base); \
            const bool msk = (mr[reg] >> (4 * col + km)) & 1ull; \
            pk[km] = msk ? 0.f : __builtin_amdgcn_exp2f(tt); \
        } \
        uint2 u; \
        u.x = pack_f16x2(pk[0], pk[1]); \
        u.y = pack_f16x2(pk[2], pk[3]); \
        *reinterpret_cast<uint2*>(&ps[PSEL][16 * w + quad * 4 + reg][4 * col]) = u; \
    } \
    if (MOK) { LOADM(MJ); if (h == 0) LOADB(MJ); } \
    FENCED_BARRIER(); \
    __builtin_amdgcn_s_setprio(1); \
    _Pragma("unroll") \
    for (int ks = 0; ks < 2; ++ks) { _Pragma("unroll") \
        for (int qs = 0; qs < 4; ++qs) { \
            const f16x8 pa = *reinterpret_cast<const f16x8*>( \
                &ps[PSEL][64 * wq + 16 * qs + col][ks * 32 + quad * 8]); \
            if (qs == wd) \
                Lacc = __builtin_amdgcn_mfma_f32_16x16x32_f16(pa, onesv, Lacc, 0, 0, 0); \
            O[qs][0] = __builtin_amdgcn_mfma_f32_16x16x32_f16(pa, vbT[0][ks], O[qs][0], 0, 0, 0); \
            O[qs][1] = __builtin_amdgcn_mfma_f32_16x16x32_f16(pa, vbT[1][ks], O[qs][1], 0, 0, 0); \
        } } \
    __builtin_amdgcn_s_setprio(0); \
} while (0)

__global__ __launch_bounds__(512, 2) void attn_kernel(
    const f16* __restrict__ QKf, const f16* __restrict__ Vt,
    const u64* __restrict__ mbits, const float* __restrict__ bias,
    f16* __restrict__ R, f16* __restrict__ part, float* __restrict__ lsum) {
    const int h  = blockIdx.y;
    const int q0 = blockIdx.x * 128;
    const int t  = threadIdx.x;
    const int w = t >> 6, lane = t & 63, quad = lane >> 4, col = lane & 15;
    const int wd = w & 3, wq = w >> 2;   // PV: d-slice / q-half

    __shared__ f16 ps[2][128][72];  // double-buffered P tile (128 q rows)
    __shared__ float ls[128];       // row sums for final normalization

    const f16x8 qa = *reinterpret_cast<const f16x8*>(
        &QKf[(size_t)(q0 + 16 * w + col) * 512 + h * 32 + quad * 8]);

    const f32x4 zero = {0.f, 0.f, 0.f, 0.f};
    // O[qs][t2]: q = q0 + 64*wq + 16*qs + quad*4 + reg, d = 32*wd + 16*t2 + col
    f32x4 O[4][2];
#pragma unroll
    for (int qs = 0; qs < 4; ++qs) { O[qs][0] = zero; O[qs][1] = zero; }
    f32x4 Lacc = zero;               // row sums for q rows [16w, 16w+16)
    const f16 one1 = (f16)1.f;
    const f16x8 onesv = {one1, one1, one1, one1, one1, one1, one1, one1};

    const float L2E = 1.4426950408889634f;
    const float SCL = 0.17677669529663687f * 1.4426950408889634f;  // scale*log2e
    const float C8  = -8.f * 1.4426950408889634f;                  // -MFIX*log2e
    const int jspan = N_NODES / gridDim.z;
    const int jbegin = blockIdx.z * jspan, jend = jbegin + jspan;

    f16x8 kbA[4], kbB[4];
    f16x8 vbT[2][2];
    u64   mr[4];
    float bfr[4][4];

    // prologue: two tiles of K, one tile of mask/bias (V loads in-tile)
    LOADK(kbA, jbegin);
    LOADK(kbB, jbegin + 64);
    LOADM(jbegin);
    if (h == 0) LOADB(jbegin);

    for (int j0 = jbegin; j0 < jend; j0 += 128) {
        TILE(kbA, 0, j0 + 128, j0 + 128 < jend, j0,      j0 + 64,  true);
        TILE(kbB, 1, j0 + 192, j0 + 192 < jend, j0 + 64, j0 + 128, j0 + 128 < jend);
    }

    // --- exchange row sums, normalize, store ---
    if (col == 0) {
#pragma unroll
        for (int reg = 0; reg < 4; ++reg)
            ls[16 * w + quad * 4 + reg] = Lacc[reg];
    }
    __syncthreads();

    if (gridDim.z == 1) {
#pragma unroll
        for (int qs = 0; qs < 4; ++qs)
#pragma unroll
            for (int reg = 0; reg < 4; ++reg) {
                const int qr = 64 * wq + 16 * qs + quad * 4 + reg;
                const float inv = 1.f / ls[qr];
                const int q = q0 + qr;
#pragma unroll
                for (int t2 = 0; t2 < 2; ++t2)
                    R[(size_t)q * VH + h * 128 + 32 * wd + 16 * t2 + col] =
                        (f16)(O[qs][t2][reg] * inv);
            }
    } else {
        const size_t seg = (size_t)(blockIdx.z * NHEAD + h) * N_NODES;
#pragma unroll
        for (int qs = 0; qs < 4; ++qs)
#pragma unroll
            for (int reg = 0; reg < 4; ++reg) {
                const int qr = 64 * wq + 16 * qs + quad * 4 + reg;
                const float inv = 1.f / ls[qr];
                const int q = q0 + qr;
#pragma unroll
                for (int t2 = 0; t2 < 2; ++t2)
                    part[(seg + q) * 128 + 32 * wd + 16 * t2 + col] =
                        (f16)(O[qs][t2][reg] * inv);
            }
        if (col == 0) {
#pragma unroll
            for (int reg = 0; reg < 4; ++reg)
                lsum[seg + q0 + 16 * w + quad * 4 + reg] = Lacc[reg];
        }
    }
}

// ---- merge split partials: R = sum_z l_z*Obar_z / sum_z l_z --------------
// vectorized: 8 d-elements per thread (f16x8 loads/stores)
__global__ __launch_bounds__(256) void merge_kernel(
    const f16* __restrict__ part, const float* __restrict__ lsum,
    f16* __restrict__ R, int split) {
    const int tid = blockIdx.x * 256 + threadIdx.x;   // 8*4096*16
    const int d8 = tid & 15, q = (tid >> 4) & 4095, h = tid >> 16;
    float acc[8];
#pragma unroll
    for (int i = 0; i < 8; ++i) acc[i] = 0.f;
    float den = 0.f;
    for (int z = 0; z < split; ++z) {
        const size_t seg = (size_t)(z * NHEAD + h) * N_NODES + q;
        const float l = lsum[seg];
        const f16x8 v = *reinterpret_cast<const f16x8*>(&part[seg * 128 + 8 * d8]);
#pragma unroll
        for (int i = 0; i < 8; ++i) acc[i] += l * (float)v[i];
        den += l;
    }
    const float inv = 1.f / den;
    f16x8 o;
#pragma unroll
    for (int i = 0; i < 8; ++i) o[i] = (f16)(acc[i] * inv);
    *reinterpret_cast<f16x8*>(&R[(size_t)q * VH + h * 128 + 8 * d8]) = o;
}

// ---- reduce out-proj k-split partials + bias (float4) --------------------
__global__ __launch_bounds__(256) void reduce_out_kernel(
    const float* __restrict__ part, const float* __restrict__ bo,
    float* __restrict__ out) {
    const int i = (blockIdx.x * 256 + threadIdx.x) * 4;   // 4096*128 floats
    float4 s = *reinterpret_cast<const float4*>(&bo[i & 127]);
#pragma unroll
    for (int z = 0; z < 4; ++z) {
        const float4 p = *reinterpret_cast<const float4*>(
            &part[(size_t)z * N_NODES * D_MODEL + i]);
        s.x += p.x; s.y += p.y; s.z += p.z; s.w += p.w;
    }
    *reinterpret_cast<float4*>(&out[i]) = s;
}

extern "C" void kernel_launch(void* const* d_in, const int* in_sizes, int n_in,
                              void* d_out, int out_size, void* d_ws, size_t ws_size,
                              hipStream_t stream) {
    const float* x  = (const float*)d_in[0];
    const int*   mk = (const int*)d_in[1];
    const float* eb = (const float*)d_in[2];
    const float* Wq = (const float*)d_in[3];
    const float* bq = (const float*)d_in[4];
    const float* Wk = (const float*)d_in[5];
    const float* bk = (const float*)d_in[6];
    const float* Wv = (const float*)d_in[7];
    const float* bv = (const float*)d_in[8];
    const float* Wo = (const float*)d_in[9];
    const float* bo = (const float*)d_in[10];
    float* out = (float*)d_out;

    char* ws = (char*)d_ws;
    u64* mbits = (u64*)(ws);                                    // 2 MB
    f16* xf16 = (f16*)(ws + 2097152);                           // 1 MB
    f16* Wqkt = (f16*)(ws + 3145728);                           // 128 KB
    f16* Wvt  = (f16*)(ws + 3276800);                           // 256 KB
    f16* Wot  = (f16*)(ws + 3538944);                           // 256 KB
    f16* QKf  = (f16*)(ws + 3801088);                           // 4 MB
    f16* Vt   = (f16*)(ws + 7995392);                           // 8 MB
    f16* Rf   = (f16*)(ws + 16384000);                          // 8 MB -> 24772608
    float* out_part = (float*)(ws + 24772608);                  // 8 MB -> 33161216
    float* lsum = (float*)(ws + 33161216);                      // 512 KB -> 33685504
    f16* part = (f16*)(ws + 33685504);                          // split*8MB -> 67239936

    // config from ws_size only (constant across calls -> graph-safe)
    int split = 1;
    if (ws_size >= 67239936ull) split = 4;
    else if (ws_size >= 50462720ull) split = 2;
    const bool ksplit_out = ws_size >= 33161216ull;

    prep_kernel<<<2560, 256, 0, stream>>>(mk, mbits, x, xf16, Wq, Wk, Wqkt, Wv, Wvt, Wo, Wot);

    proj_kernel<<<dim3(24, 64), 256, 0, stream>>>(xf16, Wqkt, Wvt, bq, bk, bv, QKf, Vt);

    attn_kernel<<<dim3(32, 8, split), 512, 0, stream>>>(QKf, Vt, mbits, eb, Rf, part, lsum);
    if (split > 1)
        merge_kernel<<<2048, 256, 0, stream>>>(part, lsum, Rf, split);

    if (ksplit_out) {
        outproj_kernel<<<dim3(2, 64, 4), 256, 0, stream>>>(Rf, Wot, out_part);
        reduce_out_kernel<<<512, 256, 0, stream>>>(out_part, bo, out);
    } else {
        // fallback: single-pass out-projection via k-split of 1
        outproj_kernel<<<dim3(2, 64, 1), 256, 0, stream>>>(Rf, Wot, out_part);
        reduce_out_kernel<<<512, 256, 0, stream>>>(out_part, bo, out);
    }
}

// Round 9
// 299.175 us; speedup vs baseline: 1.8419x; 1.2283x over previous
//
#include <hip/hip_runtime.h>

#define N_NODES 4096
#define D_MODEL 128
#define QK_DIM  32
#define NHEAD   8
#define QKH     (QK_DIM * NHEAD)   // 256
#define VH      (D_MODEL * NHEAD)  // 1024

typedef _Float16 f16;
typedef _Float16 f16x8 __attribute__((ext_vector_type(8)));
typedef float    f32x4 __attribute__((ext_vector_type(4)));
typedef unsigned long long u64;

static __device__ __forceinline__ unsigned int pack_f16x2(float a, float b) {
    union { f16 h; unsigned short s; } ua, ub;
    ua.h = (f16)a; ub.h = (f16)b;
    return ((unsigned int)ub.s << 16) | (unsigned int)ua.s;
}

// ---- fused prep: mask->bits | x->f16 | Wq,Wk->Wqkt | Wv->Wvt | Wo->Wot ----
__global__ __launch_bounds__(256) void prep_kernel(
    const int* __restrict__ mask, u64* __restrict__ mbits,
    const float* __restrict__ x, f16* __restrict__ xf,
    const float* __restrict__ Wq, const float* __restrict__ Wk,
    f16* __restrict__ Wqkt,
    const float* __restrict__ Wv, f16* __restrict__ Wvt,
    const float* __restrict__ Wo, f16* __restrict__ Wot) {
    const int b = blockIdx.x, t = threadIdx.x;
    if (b < 1024) {
        const int gw = b * 4 + (t >> 6), lane = t & 63;
        for (int word = gw; word < 262144; word += 4096) {
            const int v = mask[(size_t)word * 64 + lane];
            const u64 bits = __ballot(v != 0);
            if (lane == 0) mbits[word] = bits;
        }
    } else if (b < 1280) {
        const int tid = (b - 1024) * 256 + t;
        const float2* x2 = (const float2*)x;
        unsigned int* u = (unsigned int*)xf;
        for (int i = tid; i < 262144; i += 65536) {
            const float2 v = x2[i];
            u[i] = pack_f16x2(v.x, v.y);
        }
    } else if (b < 1408) {
        const int tid = (b - 1280) * 256 + t;           // 32768 elems
        const int n = tid >> 7, k = tid & 127;
        Wqkt[tid] = (f16)Wq[(size_t)k * QKH + n];
    } else if (b < 1536) {
        const int tid = (b - 1408) * 256 + t;           // 32768 elems
        const int n = tid >> 7, k = tid & 127;
        Wqkt[32768 + tid] = (f16)Wk[(size_t)k * QKH + n];
    } else if (b < 2048) {
        const int tid = (b - 1536) * 256 + t;           // 131072 elems
        const int n = tid >> 7, k = tid & 127;
        Wvt[tid] = (f16)Wv[(size_t)k * VH + n];
    } else {
        const int tid = (b - 2048) * 256 + t;           // 131072 elems
        const int n = tid >> 10, k = tid & 1023;
        Wot[tid] = (f16)Wo[(size_t)k * D_MODEL + n];
    }
}

// ---- GEMM body: C[M,N] = A[M,K](f16) @ Wt[N,K]^T (+bias) -----------------
// MODE 1: V-proj -> Vf FRAGMENT-LINEAR (LDS bounce, coalesced stores)
// MODE 3: f32 partials (no bias), k-split by bz, out offset bz*M*N
// MODE 4: QK-proj -> Qf[m][256] (n<256) + Kf FRAGMENT-LINEAR (n>=256)
// Fragment layouts (match attn's MFMA fragments exactly; lane=quad*16+col):
//   Kf 16B unit fidx = ((h*64+jblk)*4+km)*64 + lane
//      holds K[key=jblk*64+4*col+km][d=h*32+quad*8 .. +7]
//   Vf 16B unit gidx = (((h*64+jblk)*4+wd)*4+t2*2+ks)*64 + lane
//      holds V^T[hd=h*128+32*wd+16*t2+col][key=jblk*64+ks*32+quad*8 .. +7]
template <int OUT_MODE, bool DUAL_BIAS>
static __device__ __forceinline__ void gemm_body(
    const f16* __restrict__ A, const f16* __restrict__ Wt,
    const float* __restrict__ b1, const float* __restrict__ b2,
    void* __restrict__ outp, int M, int N, int K,
    int bx, int by, int bz, int nz, void* __restrict__ outp2 = nullptr) {
    const int t = threadIdx.x;
    const int w = t >> 6, lane = t & 63, quad = lane >> 4, col = lane & 15;
    const int mb = by * 64 + (w & 1) * 32;
    const int nb = bx * 64 + (w >> 1) * 32;

    const f32x4 zero = {0.f, 0.f, 0.f, 0.f};
    f32x4 acc[2][2];
    acc[0][0] = zero; acc[0][1] = zero; acc[1][0] = zero; acc[1][1] = zero;

    const int ksteps = K >> 5;
    const int kper = ksteps / nz;
    const int ks0 = bz * kper, ks1 = ks0 + kper;
    for (int ks = ks0; ks < ks1; ++ks) {
        const int ko = ks * 32 + quad * 8;
        const f16x8 a0 = *reinterpret_cast<const f16x8*>(&A[(size_t)(mb + col) * K + ko]);
        const f16x8 a1 = *reinterpret_cast<const f16x8*>(&A[(size_t)(mb + 16 + col) * K + ko]);
        const f16x8 b0 = *reinterpret_cast<const f16x8*>(&Wt[(size_t)(nb + col) * K + ko]);
        const f16x8 bb = *reinterpret_cast<const f16x8*>(&Wt[(size_t)(nb + 16 + col) * K + ko]);
        acc[0][0] = __builtin_amdgcn_mfma_f32_16x16x32_f16(a0, b0, acc[0][0], 0, 0, 0);
        acc[1][0] = __builtin_amdgcn_mfma_f32_16x16x32_f16(a1, b0, acc[1][0], 0, 0, 0);
        acc[0][1] = __builtin_amdgcn_mfma_f32_16x16x32_f16(a0, bb, acc[0][1], 0, 0, 0);
        acc[1][1] = __builtin_amdgcn_mfma_f32_16x16x32_f16(a1, bb, acc[1][1], 0, 0, 0);
    }

    if constexpr (OUT_MODE == 1) {
        __shared__ f16 ct[64][68];
#pragma unroll
        for (int sub = 0; sub < 2; ++sub)
#pragma unroll
            for (int snb = 0; snb < 2; ++snb) {
                const int nl = (w >> 1) * 32 + snb * 16 + col;
                const float bv = b1[nb + snb * 16 + col];
                const int ml0 = (w & 1) * 32 + sub * 16 + quad * 4;
                uint2 u;
                u.x = pack_f16x2(acc[sub][snb][0] + bv, acc[sub][snb][1] + bv);
                u.y = pack_f16x2(acc[sub][snb][2] + bv, acc[sub][snb][3] + bv);
                *reinterpret_cast<uint2*>(&ct[nl][ml0]) = u;
            }
        __syncthreads();
        const int nl = t >> 2, qtr = t & 3;
        const int n = bx * 64 + nl;          // hd index 0..1023
        const int m0 = by * 64 + qtr * 16;   // key base
        const f16x8 v0 = *reinterpret_cast<const f16x8*>(&ct[nl][qtr * 16]);
        const f16x8 v1 = *reinterpret_cast<const f16x8*>(&ct[nl][qtr * 16 + 8]);
        const int hh = n >> 7, dd = n & 127;
        const int wdv = dd >> 5, t2v = (dd >> 4) & 1, colv = dd & 15;
        {   // v0: keys m0..m0+7
            const int m = m0;
            const int jb = m >> 6, ksv = (m >> 5) & 1, qv = (m >> 3) & 3;
            const size_t gidx = ((size_t)((((hh * 64 + jb) * 4 + wdv) * 4) + t2v * 2 + ksv)) * 64 + qv * 16 + colv;
            *reinterpret_cast<f16x8*>(&((f16*)outp)[gidx * 8]) = v0;
        }
        {   // v1: keys m0+8..m0+15
            const int m = m0 + 8;
            const int jb = m >> 6, ksv = (m >> 5) & 1, qv = (m >> 3) & 3;
            const size_t gidx = ((size_t)((((hh * 64 + jb) * 4 + wdv) * 4) + t2v * 2 + ksv)) * 64 + qv * 16 + colv;
            *reinterpret_cast<f16x8*>(&((f16*)outp)[gidx * 8]) = v1;
        }
    } else if constexpr (OUT_MODE == 4) {
        f16* Qf = (f16*)outp;
        f16* Kf = (f16*)outp2;
#pragma unroll
        for (int sub = 0; sub < 2; ++sub)
#pragma unroll
            for (int snb = 0; snb < 2; ++snb) {
                const int n = nb + snb * 16 + col;
                const float bv = (DUAL_BIAS && n >= 256) ? b2[n - 256] : b1[n];
#pragma unroll
                for (int reg = 0; reg < 4; ++reg) {
                    const int m = mb + sub * 16 + quad * 4 + reg;
                    const float v  = acc[sub][snb][reg] + bv;
                    const float v2 = __shfl_xor(v, 1);
                    if ((lane & 1) == 0) {
                        const int n0 = n & ~1;
                        f16* dst;
                        if (n0 < 256) {
                            dst = &Qf[(size_t)m * 256 + n0];
                        } else {
                            const int d32 = n0 - 256;
                            const int hh = d32 >> 5, dd = d32 & 31;
                            const int lane_k = (dd >> 3) * 16 + ((m >> 2) & 15);
                            const size_t fidx = ((size_t)((hh * 64 + (m >> 6)) * 4 + (m & 3))) * 64 + lane_k;
                            dst = &Kf[fidx * 8 + (dd & 7)];
                        }
                        *reinterpret_cast<unsigned int*>(dst) = pack_f16x2(v, v2);
                    }
                }
            }
    } else {
#pragma unroll
        for (int sub = 0; sub < 2; ++sub)
#pragma unroll
            for (int snb = 0; snb < 2; ++snb) {
                const int n = nb + snb * 16 + col;
                float* ob = (float*)outp + (size_t)bz * M * N;
#pragma unroll
                for (int reg = 0; reg < 4; ++reg) {
                    const int m = mb + sub * 16 + quad * 4 + reg;
                    ob[(size_t)m * N + n] = acc[sub][snb][reg];
                }
            }
    }
}

// ---- fused QK + V projections (one launch, 24x64 grid) -------------------
__global__ __launch_bounds__(256) void proj_kernel(
    const f16* __restrict__ xf, const f16* __restrict__ Wqkt,
    const f16* __restrict__ Wvt,
    const float* __restrict__ bq, const float* __restrict__ bk,
    const float* __restrict__ bv,
    f16* __restrict__ Qf, f16* __restrict__ Kf, f16* __restrict__ Vf) {
    if (blockIdx.x < 8)
        gemm_body<4, true>(xf, Wqkt, bq, bk, Qf, N_NODES, 512, D_MODEL,
                           blockIdx.x, blockIdx.y, 0, 1, Kf);
    else
        gemm_body<1, false>(xf, Wvt, bv, bv, Vf, N_NODES, VH, D_MODEL,
                            blockIdx.x - 8, blockIdx.y, 0, 1);
}

// ---- out-projection with k-split -----------------------------------------
__global__ __launch_bounds__(256) void outproj_kernel(
    const f16* __restrict__ Rf, const f16* __restrict__ Wot,
    float* __restrict__ outp) {
    gemm_body<3, false>(Rf, Wot, nullptr, nullptr, outp, N_NODES, D_MODEL, VH,
                        blockIdx.x, blockIdx.y, blockIdx.z, gridDim.z);
}

// ---- MFMA flash attention, software-pipelined, fenced raw barriers -------
// Grid (64 q-tiles, 8 heads, split). Block 256 = 4 waves.
// HISTORY (do not revisit):
//   R1 (256,3) 2-deep K+V: 285MB spill, 252us. R2/R3 (256,2): WRONG,
//   fence-independent -> (256,2) regime miscompiles. R5 (256,3) 2-deep K +
//   in-tile V: CORRECT 172.8us (BEST). R6 (256,4): 573MB spill, 366us.
//   R7 V-ahead dbuf: NaN -> register-pipeline edits around the fenced
//   barrier are a fragile compile regime; R5 sync structure FROZEN.
//   R8 128-q-tile (V traffic halved): 177us, no change -> attn is NOT
//   L2/L3-BW bound. ~6600cy/tile vs ~2700 accounted -> stall is VMEM
//   gather issue (16 scattered cache lines per K/V load) + in-phase burst.
// THIS VERSION: R5 skeleton byte-for-byte; ONLY load addresses changed.
//   K and V are now stored FRAGMENT-LINEAR by proj (see gemm_body header),
//   so every LOADK/LOADV instr is base + lane*16B = one contiguous 1KB
//   transaction. Pure layout bijection; no sync/register change.
#define FENCED_BARRIER() do { \
    asm volatile("s_waitcnt lgkmcnt(0)\n\ts_barrier" ::: "memory"); \
    __builtin_amdgcn_sched_barrier(0); \
} while (0)

#define LOADK(KB, J) do { _Pragma("unroll") \
    for (int km = 0; km < 4; ++km) \
        KB[km] = *reinterpret_cast<const f16x8*>( \
            &Kf[((size_t)((h * 64 + ((J) >> 6)) * 4 + km) * 64 + lane) * 8]); } while (0)

#define LOADV(VB, J) do { _Pragma("unroll") \
    for (int t2 = 0; t2 < 2; ++t2) { _Pragma("unroll") \
        for (int ks = 0; ks < 2; ++ks) \
            VB[t2][ks] = *reinterpret_cast<const f16x8*>( \
                &Vf[((size_t)(((h * 64 + ((J) >> 6)) * 4 + w) * 4 + t2 * 2 + ks) * 64 + lane) * 8]); } } while (0)

#define LOADM(J) do { _Pragma("unroll") \
    for (int reg = 0; reg < 4; ++reg) \
        mr[reg] = mbits[(size_t)(q0 + 16 * w + quad * 4 + reg) * 64 + ((J) >> 6)]; } while (0)

#define LOADB(J) do { _Pragma("unroll") \
    for (int reg = 0; reg < 4; ++reg) { \
        const float4 b4 = *reinterpret_cast<const float4*>( \
            &bias[(size_t)(q0 + 16 * w + quad * 4 + reg) * N_NODES + (J) + 4 * col]); \
        bfr[reg][0] = b4.x; bfr[reg][1] = b4.y; \
        bfr[reg][2] = b4.z; bfr[reg][3] = b4.w; } } while (0)

// One 64-key tile. KB: this tile's K register set (also prefetch target two
// tiles ahead). PSEL: LDS ps buffer (0/1). PJ/POK: K prefetch j + guard.
// VJ: current tile j for the shared V set. MJ/MOK: mask/bias prefetch.
#define TILE(KB, PSEL, PJ, POK, VJ, MJ, MOK) do { \
    f32x4 S[4]; \
    _Pragma("unroll") \
    for (int km = 0; km < 4; ++km) \
        S[km] = __builtin_amdgcn_mfma_f32_16x16x32_f16(qa, KB[km], zero, 0, 0, 0); \
    if (POK) LOADK(KB, PJ); \
    LOADV(vbT, VJ); \
    _Pragma("unroll") \
    for (int reg = 0; reg < 4; ++reg) { \
        float pk[4]; \
        _Pragma("unroll") \
        for (int km = 0; km < 4; ++km) { \
            float base = C8; \
            if (h == 0) base = __builtin_fmaf(bfr[reg][km], L2E, C8); \
            const float tt = __builtin_fmaf(S[km][reg], SCL, base); \
            const bool msk = (mr[reg] >> (4 * col + km)) & 1ull; \
            pk[km] = msk ? 0.f : __builtin_amdgcn_exp2f(tt); \
        } \
        uint2 u; \
        u.x = pack_f16x2(pk[0], pk[1]); \
        u.y = pack_f16x2(pk[2], pk[3]); \
        *reinterpret_cast<uint2*>(&ps[PSEL][16 * w + quad * 4 + reg][4 * col]) = u; \
    } \
    if (MOK) { LOADM(MJ); if (h == 0) LOADB(MJ); } \
    FENCED_BARRIER(); \
    __builtin_amdgcn_s_setprio(1); \
    _Pragma("unroll") \
    for (int ks = 0; ks < 2; ++ks) { _Pragma("unroll") \
        for (int qs = 0; qs < 4; ++qs) { \
            const f16x8 pa = *reinterpret_cast<const f16x8*>( \
                &ps[PSEL][16 * qs + col][ks * 32 + quad * 8]); \
            if (qs == w) \
                Lacc = __builtin_amdgcn_mfma_f32_16x16x32_f16(pa, onesv, Lacc, 0, 0, 0); \
            O[qs][0] = __builtin_amdgcn_mfma_f32_16x16x32_f16(pa, vbT[0][ks], O[qs][0], 0, 0, 0); \
            O[qs][1] = __builtin_amdgcn_mfma_f32_16x16x32_f16(pa, vbT[1][ks], O[qs][1], 0, 0, 0); \
        } } \
    __builtin_amdgcn_s_setprio(0); \
} while (0)

__global__ __launch_bounds__(256, 3) void attn_kernel(
    const f16* __restrict__ Qf, const f16* __restrict__ Kf,
    const f16* __restrict__ Vf,
    const u64* __restrict__ mbits, const float* __restrict__ bias,
    f16* __restrict__ R, f16* __restrict__ part, float* __restrict__ lsum) {
    const int h  = blockIdx.y;
    const int q0 = blockIdx.x * 64;
    const int t  = threadIdx.x;
    const int w = t >> 6, lane = t & 63, quad = lane >> 4, col = lane & 15;

    __shared__ f16 ps[2][64][72];   // double-buffered P tile
    __shared__ float ls[64];        // row sums for final normalization

    const f16x8 qa = *reinterpret_cast<const f16x8*>(
        &Qf[(size_t)(q0 + 16 * w + col) * 256 + h * 32 + quad * 8]);

    const f32x4 zero = {0.f, 0.f, 0.f, 0.f};
    f32x4 O[4][2];               // [qs][t2]: q 16qs+quad*4+reg, d 32w+16t2+col
#pragma unroll
    for (int qs = 0; qs < 4; ++qs) { O[qs][0] = zero; O[qs][1] = zero; }
    f32x4 Lacc = zero;
    const f16 one1 = (f16)1.f;
    const f16x8 onesv = {one1, one1, one1, one1, one1, one1, one1, one1};

    const float L2E = 1.4426950408889634f;
    const float SCL = 0.17677669529663687f * 1.4426950408889634f;  // scale*log2e
    const float C8  = -8.f * 1.4426950408889634f;                  // -MFIX*log2e
    const int jspan = N_NODES / gridDim.z;
    const int jbegin = blockIdx.z * jspan, jend = jbegin + jspan;

    f16x8 kbA[4], kbB[4];
    f16x8 vbT[2][2];
    u64   mr[4];
    float bfr[4][4];

    // prologue: two tiles of K, one tile of mask/bias (V loads in-tile)
    LOADK(kbA, jbegin);
    LOADK(kbB, jbegin + 64);
    LOADM(jbegin);
    if (h == 0) LOADB(jbegin);

    for (int j0 = jbegin; j0 < jend; j0 += 128) {
        TILE(kbA, 0, j0 + 128, j0 + 128 < jend, j0,      j0 + 64,  true);
        TILE(kbB, 1, j0 + 192, j0 + 192 < jend, j0 + 64, j0 + 128, j0 + 128 < jend);
    }

    // --- exchange row sums, normalize, store ---
    if (col == 0) {
#pragma unroll
        for (int reg = 0; reg < 4; ++reg)
            ls[16 * w + quad * 4 + reg] = Lacc[reg];
    }
    __syncthreads();

    if (gridDim.z == 1) {
#pragma unroll
        for (int qs = 0; qs < 4; ++qs)
#pragma unroll
            for (int reg = 0; reg < 4; ++reg) {
                const float inv = 1.f / ls[16 * qs + quad * 4 + reg];
                const int q = q0 + 16 * qs + quad * 4 + reg;
#pragma unroll
                for (int t2 = 0; t2 < 2; ++t2)
                    R[(size_t)q * VH + h * 128 + 32 * w + 16 * t2 + col] =
                        (f16)(O[qs][t2][reg] * inv);
            }
    } else {
        const size_t seg = (size_t)(blockIdx.z * NHEAD + h) * N_NODES;
#pragma unroll
        for (int qs = 0; qs < 4; ++qs)
#pragma unroll
            for (int reg = 0; reg < 4; ++reg) {
                const float inv = 1.f / ls[16 * qs + quad * 4 + reg];
                const int q = q0 + 16 * qs + quad * 4 + reg;
#pragma unroll
                for (int t2 = 0; t2 < 2; ++t2)
                    part[(seg + q) * 128 + 32 * w + 16 * t2 + col] =
                        (f16)(O[qs][t2][reg] * inv);
            }
        if (col == 0) {
#pragma unroll
            for (int reg = 0; reg < 4; ++reg)
                lsum[seg + q0 + 16 * w + quad * 4 + reg] = Lacc[reg];
        }
    }
}

// ---- merge split partials: R = sum_z l_z*Obar_z / sum_z l_z --------------
// vectorized: 8 d-elements per thread (f16x8 loads/stores)
__global__ __launch_bounds__(256) void merge_kernel(
    const f16* __restrict__ part, const float* __restrict__ lsum,
    f16* __restrict__ R, int split) {
    const int tid = blockIdx.x * 256 + threadIdx.x;   // 8*4096*16
    const int d8 = tid & 15, q = (tid >> 4) & 4095, h = tid >> 16;
    float acc[8];
#pragma unroll
    for (int i = 0; i < 8; ++i) acc[i] = 0.f;
    float den = 0.f;
    for (int z = 0; z < split; ++z) {
        const size_t seg = (size_t)(z * NHEAD + h) * N_NODES + q;
        const float l = lsum[seg];
        const f16x8 v = *reinterpret_cast<const f16x8*>(&part[seg * 128 + 8 * d8]);
#pragma unroll
        for (int i = 0; i < 8; ++i) acc[i] += l * (float)v[i];
        den += l;
    }
    const float inv = 1.f / den;
    f16x8 o;
#pragma unroll
    for (int i = 0; i < 8; ++i) o[i] = (f16)(acc[i] * inv);
    *reinterpret_cast<f16x8*>(&R[(size_t)q * VH + h * 128 + 8 * d8]) = o;
}

// ---- reduce out-proj k-split partials + bias (float4) --------------------
__global__ __launch_bounds__(256) void reduce_out_kernel(
    const float* __restrict__ part, const float* __restrict__ bo,
    float* __restrict__ out) {
    const int i = (blockIdx.x * 256 + threadIdx.x) * 4;   // 4096*128 floats
    float4 s = *reinterpret_cast<const float4*>(&bo[i & 127]);
#pragma unroll
    for (int z = 0; z < 4; ++z) {
        const float4 p = *reinterpret_cast<const float4*>(
            &part[(size_t)z * N_NODES * D_MODEL + i]);
        s.x += p.x; s.y += p.y; s.z += p.z; s.w += p.w;
    }
    *reinterpret_cast<float4*>(&out[i]) = s;
}

extern "C" void kernel_launch(void* const* d_in, const int* in_sizes, int n_in,
                              void* d_out, int out_size, void* d_ws, size_t ws_size,
                              hipStream_t stream) {
    const float* x  = (const float*)d_in[0];
    const int*   mk = (const int*)d_in[1];
    const float* eb = (const float*)d_in[2];
    const float* Wq = (const float*)d_in[3];
    const float* bq = (const float*)d_in[4];
    const float* Wk = (const float*)d_in[5];
    const float* bk = (const float*)d_in[6];
    const float* Wv = (const float*)d_in[7];
    const float* bv = (const float*)d_in[8];
    const float* Wo = (const float*)d_in[9];
    const float* bo = (const float*)d_in[10];
    float* out = (float*)d_out;

    char* ws = (char*)d_ws;
    u64* mbits = (u64*)(ws);                                    // 2 MB
    f16* xf16 = (f16*)(ws + 2097152);                           // 1 MB
    f16* Wqkt = (f16*)(ws + 3145728);                           // 128 KB
    f16* Wvt  = (f16*)(ws + 3276800);                           // 256 KB
    f16* Wot  = (f16*)(ws + 3538944);                           // 256 KB
    f16* Qf   = (f16*)(ws + 3801088);                           // 2 MB (node x 256)
    f16* Kf   = (f16*)(ws + 5898240);                           // 2 MB fragment-linear
    f16* Vf   = (f16*)(ws + 7995392);                           // 8 MB fragment-linear
    f16* Rf   = (f16*)(ws + 16384000);                          // 8 MB -> 24772608
    float* out_part = (float*)(ws + 24772608);                  // 8 MB -> 33161216
    float* lsum = (float*)(ws + 33161216);                      // 512 KB -> 33685504
    f16* part = (f16*)(ws + 33685504);                          // split*8MB -> 67239936

    // config from ws_size only (constant across calls -> graph-safe)
    int split = 1;
    if (ws_size >= 67239936ull) split = 4;
    else if (ws_size >= 50462720ull) split = 2;
    const bool ksplit_out = ws_size >= 33161216ull;

    prep_kernel<<<2560, 256, 0, stream>>>(mk, mbits, x, xf16, Wq, Wk, Wqkt, Wv, Wvt, Wo, Wot);

    proj_kernel<<<dim3(24, 64), 256, 0, stream>>>(xf16, Wqkt, Wvt, bq, bk, bv, Qf, Kf, Vf);

    attn_kernel<<<dim3(64, 8, split), 256, 0, stream>>>(Qf, Kf, Vf, mbits, eb, Rf, part, lsum);
    if (split > 1)
        merge_kernel<<<2048, 256, 0, stream>>>(part, lsum, Rf, split);

    if (ksplit_out) {
        outproj_kernel<<<dim3(2, 64, 4), 256, 0, stream>>>(Rf, Wot, out_part);
        reduce_out_kernel<<<512, 256, 0, stream>>>(out_part, bo, out);
    } else {
        // fallback: single-pass out-projection via k-split of 1
        outproj_kernel<<<dim3(2, 64, 1), 256, 0, stream>>>(Rf, Wot, out_part);
        reduce_out_kernel<<<512, 256, 0, stream>>>(out_part, bo, out);
    }
}